// Round 1
// baseline (320.008 us; speedup 1.0000x reference)
//
#include <hip/hip_runtime.h>

#define CH 16
#define NPIX (4 * 512 * 512)

// ---------------------------------------------------------------------------
// Repack one pyramid layer from [C, H, W] to [H, W, C] (channel-interleaved)
// so that one texel = 64 B contiguous and a bilinear tap reads 2x128 B.
// Reads are coalesced (consecutive threads -> consecutive x), writes are
// contiguous 64 B per thread (4x float4).
// ---------------------------------------------------------------------------
__global__ __launch_bounds__(256) void interleave_kernel(
    const float* __restrict__ src, float* __restrict__ dst, int HW) {
  int p = blockIdx.x * blockDim.x + threadIdx.x;
  if (p >= HW) return;
  float v[CH];
#pragma unroll
  for (int c = 0; c < CH; ++c) v[c] = src[(size_t)c * HW + p];
  float4* d = (float4*)(dst + (size_t)p * CH);
#pragma unroll
  for (int c4 = 0; c4 < 4; ++c4)
    d[c4] = make_float4(v[4 * c4 + 0], v[4 * c4 + 1], v[4 * c4 + 2], v[4 * c4 + 3]);
}

// ---------------------------------------------------------------------------
// Bilinear sample of one interleaved [H, W, C] layer, accumulated into acc[4]
// (float4 per 4 channels). Replicates the reference math exactly:
// ix = (gx + 1) * 0.5 * (W-1); per-corner validity (zeros padding) computed on
// UNclamped float indices, then clamped integer gather.
// ---------------------------------------------------------------------------
__device__ __forceinline__ void sample_hwc(const float* __restrict__ t, int W,
                                           float gx, float gy, float4 acc[4]) {
  const float W1 = (float)(W - 1);
  float ix = (gx + 1.0f) * 0.5f * W1;
  float iy = (gy + 1.0f) * 0.5f * W1;
  float ix0f = floorf(ix), iy0f = floorf(iy);
  float wx1 = ix - ix0f, wy1 = iy - iy0f;
  float wx0 = 1.0f - wx1, wy0 = 1.0f - wy1;
  float ix1f = ix0f + 1.0f, iy1f = iy0f + 1.0f;
  float vx0 = (ix0f >= 0.0f && ix0f <= W1) ? 1.0f : 0.0f;
  float vx1 = (ix1f >= 0.0f && ix1f <= W1) ? 1.0f : 0.0f;
  float vy0 = (iy0f >= 0.0f && iy0f <= W1) ? 1.0f : 0.0f;
  float vy1 = (iy1f >= 0.0f && iy1f <= W1) ? 1.0f : 0.0f;
  int x0 = min(max((int)ix0f, 0), W - 1);
  int x1 = min(max((int)ix1f, 0), W - 1);
  int y0 = min(max((int)iy0f, 0), W - 1);
  int y1 = min(max((int)iy1f, 0), W - 1);
  float w00 = wy0 * wx0 * vy0 * vx0;
  float w01 = wy0 * wx1 * vy0 * vx1;
  float w10 = wy1 * wx0 * vy1 * vx0;
  float w11 = wy1 * wx1 * vy1 * vx1;
  const float4* p00 = (const float4*)(t + ((size_t)y0 * W + x0) * CH);
  const float4* p01 = (const float4*)(t + ((size_t)y0 * W + x1) * CH);
  const float4* p10 = (const float4*)(t + ((size_t)y1 * W + x0) * CH);
  const float4* p11 = (const float4*)(t + ((size_t)y1 * W + x1) * CH);
#pragma unroll
  for (int c4 = 0; c4 < 4; ++c4) {
    float4 v00 = p00[c4], v01 = p01[c4], v10 = p10[c4], v11 = p11[c4];
    acc[c4].x = fmaf(v00.x, w00, fmaf(v01.x, w01, fmaf(v10.x, w10, fmaf(v11.x, w11, acc[c4].x))));
    acc[c4].y = fmaf(v00.y, w00, fmaf(v01.y, w01, fmaf(v10.y, w10, fmaf(v11.y, w11, acc[c4].y))));
    acc[c4].z = fmaf(v00.z, w00, fmaf(v01.z, w01, fmaf(v10.z, w10, fmaf(v11.z, w11, acc[c4].z))));
    acc[c4].w = fmaf(v00.w, w00, fmaf(v01.w, w01, fmaf(v10.w, w10, fmaf(v11.w, w11, acc[c4].w))));
  }
}

__global__ __launch_bounds__(256) void gather_hwc_kernel(
    const float* __restrict__ x, const float* __restrict__ msk,
    const float* __restrict__ t1, const float* __restrict__ t2,
    const float* __restrict__ t3, const float* __restrict__ t4,
    float* __restrict__ out) {
  int p = blockIdx.x * blockDim.x + threadIdx.x;
  int wo = p & 511, ho = (p >> 9) & 511, b = p >> 18;
  float2 g = ((const float2*)x)[p];
  float gx = g.x * 2.0f - 1.0f;
  float gy = g.y * 2.0f - 1.0f;
  float m = msk[p];
  float4 acc[4];
#pragma unroll
  for (int i = 0; i < 4; ++i) acc[i] = make_float4(0.f, 0.f, 0.f, 0.f);
  sample_hwc(t1, 1024, gx, gy, acc);
  sample_hwc(t2, 512, gx, gy, acc);
  sample_hwc(t3, 256, gx, gy, acc);
  sample_hwc(t4, 128, gx, gy, acc);
  // out[b][c][ho][wo], c-stride = 512*512
  size_t obase = (size_t)b * (CH * 262144) + (size_t)ho * 512 + wo;
#pragma unroll
  for (int c4 = 0; c4 < 4; ++c4) {
    out[obase + (size_t)(4 * c4 + 0) * 262144] = acc[c4].x * m;
    out[obase + (size_t)(4 * c4 + 1) * 262144] = acc[c4].y * m;
    out[obase + (size_t)(4 * c4 + 2) * 262144] = acc[c4].z * m;
    out[obase + (size_t)(4 * c4 + 3) * 262144] = acc[c4].w * m;
  }
}

// ---------------------------------------------------------------------------
// Fallback: direct gather from native [C, H, W] layout (if ws too small).
// ---------------------------------------------------------------------------
__device__ __forceinline__ void sample_chw(const float* __restrict__ t, int W,
                                           float gx, float gy, float acc[CH]) {
  const float W1 = (float)(W - 1);
  float ix = (gx + 1.0f) * 0.5f * W1;
  float iy = (gy + 1.0f) * 0.5f * W1;
  float ix0f = floorf(ix), iy0f = floorf(iy);
  float wx1 = ix - ix0f, wy1 = iy - iy0f;
  float wx0 = 1.0f - wx1, wy0 = 1.0f - wy1;
  float ix1f = ix0f + 1.0f, iy1f = iy0f + 1.0f;
  float vx0 = (ix0f >= 0.0f && ix0f <= W1) ? 1.0f : 0.0f;
  float vx1 = (ix1f >= 0.0f && ix1f <= W1) ? 1.0f : 0.0f;
  float vy0 = (iy0f >= 0.0f && iy0f <= W1) ? 1.0f : 0.0f;
  float vy1 = (iy1f >= 0.0f && iy1f <= W1) ? 1.0f : 0.0f;
  int x0 = min(max((int)ix0f, 0), W - 1);
  int x1 = min(max((int)ix1f, 0), W - 1);
  int y0 = min(max((int)iy0f, 0), W - 1);
  int y1 = min(max((int)iy1f, 0), W - 1);
  float w00 = wy0 * wx0 * vy0 * vx0;
  float w01 = wy0 * wx1 * vy0 * vx1;
  float w10 = wy1 * wx0 * vy1 * vx0;
  float w11 = wy1 * wx1 * vy1 * vx1;
  size_t HW = (size_t)W * W;
  const float* b00 = t + (size_t)y0 * W + x0;
  const float* b01 = t + (size_t)y0 * W + x1;
  const float* b10 = t + (size_t)y1 * W + x0;
  const float* b11 = t + (size_t)y1 * W + x1;
#pragma unroll
  for (int c = 0; c < CH; ++c) {
    float v00 = b00[c * HW], v01 = b01[c * HW], v10 = b10[c * HW], v11 = b11[c * HW];
    acc[c] = fmaf(v00, w00, fmaf(v01, w01, fmaf(v10, w10, fmaf(v11, w11, acc[c]))));
  }
}

__global__ __launch_bounds__(256) void gather_chw_kernel(
    const float* __restrict__ x, const float* __restrict__ msk,
    const float* __restrict__ l1, const float* __restrict__ l2,
    const float* __restrict__ l3, const float* __restrict__ l4,
    float* __restrict__ out) {
  int p = blockIdx.x * blockDim.x + threadIdx.x;
  int wo = p & 511, ho = (p >> 9) & 511, b = p >> 18;
  float2 g = ((const float2*)x)[p];
  float gx = g.x * 2.0f - 1.0f;
  float gy = g.y * 2.0f - 1.0f;
  float m = msk[p];
  float acc[CH];
#pragma unroll
  for (int c = 0; c < CH; ++c) acc[c] = 0.0f;
  sample_chw(l1, 1024, gx, gy, acc);
  sample_chw(l2, 512, gx, gy, acc);
  sample_chw(l3, 256, gx, gy, acc);
  sample_chw(l4, 128, gx, gy, acc);
  size_t obase = (size_t)b * (CH * 262144) + (size_t)ho * 512 + wo;
#pragma unroll
  for (int c = 0; c < CH; ++c) out[obase + (size_t)c * 262144] = acc[c] * m;
}

extern "C" void kernel_launch(void* const* d_in, const int* in_sizes, int n_in,
                              void* d_out, int out_size, void* d_ws, size_t ws_size,
                              hipStream_t stream) {
  const float* x   = (const float*)d_in[0];
  const float* msk = (const float*)d_in[1];
  const float* l1  = (const float*)d_in[2];
  const float* l2  = (const float*)d_in[3];
  const float* l3  = (const float*)d_in[4];
  const float* l4  = (const float*)d_in[5];
  float* out = (float*)d_out;

  const size_t need = (size_t)(1048576 + 262144 + 65536 + 16384) * CH * sizeof(float);
  if (ws_size >= need) {
    float* w1 = (float*)d_ws;
    float* w2 = w1 + (size_t)1048576 * CH;
    float* w3 = w2 + (size_t)262144 * CH;
    float* w4 = w3 + (size_t)65536 * CH;
    interleave_kernel<<<1048576 / 256, 256, 0, stream>>>(l1, w1, 1048576);
    interleave_kernel<<<262144 / 256, 256, 0, stream>>>(l2, w2, 262144);
    interleave_kernel<<<65536 / 256, 256, 0, stream>>>(l3, w3, 65536);
    interleave_kernel<<<16384 / 256, 256, 0, stream>>>(l4, w4, 16384);
    gather_hwc_kernel<<<NPIX / 256, 256, 0, stream>>>(x, msk, w1, w2, w3, w4, out);
  } else {
    gather_chw_kernel<<<NPIX / 256, 256, 0, stream>>>(x, msk, l1, l2, l3, l4, out);
  }
}

// Round 2
// 178.974 us; speedup vs baseline: 1.7880x; 1.7880x over previous
//
#include <hip/hip_runtime.h>
#include <hip/hip_fp16.h>

#define CH 16
#define NPIX (4 * 512 * 512)

// ---------------------------------------------------------------------------
// Repack one pyramid layer from [C, H, W] f32 to [H, W, C] fp16 (interleaved).
// One texel = 32 B contiguous; a bilinear corner = 2x dwordx4.
// ---------------------------------------------------------------------------
__global__ __launch_bounds__(256) void interleave_fp16_kernel(
    const float* __restrict__ src, __half* __restrict__ dst, int HW) {
  int p = blockIdx.x * blockDim.x + threadIdx.x;
  if (p >= HW) return;
  union { __half h[CH]; uint4 u[2]; } pk;
#pragma unroll
  for (int c = 0; c < CH; ++c) pk.h[c] = __float2half(src[(size_t)c * HW + p]);
  uint4* d = (uint4*)(dst + (size_t)p * CH);
  d[0] = pk.u[0];
  d[1] = pk.u[1];
}

// ---------------------------------------------------------------------------
// One bilinear corner: load 16 fp16 channels (2x uint4), FMA into f32 acc.
// ---------------------------------------------------------------------------
__device__ __forceinline__ void corner_fma(const __half* __restrict__ t,
                                           size_t texel, float w, float acc[CH]) {
  const uint4* q = (const uint4*)(t + texel * CH);
  union { uint4 u; __half2 h[4]; } a, b;
  a.u = q[0];
  b.u = q[1];
#pragma unroll
  for (int i = 0; i < 4; ++i) {
    float2 f = __half22float2(a.h[i]);
    acc[2 * i + 0] = fmaf(f.x, w, acc[2 * i + 0]);
    acc[2 * i + 1] = fmaf(f.y, w, acc[2 * i + 1]);
  }
#pragma unroll
  for (int i = 0; i < 4; ++i) {
    float2 f = __half22float2(b.h[i]);
    acc[8 + 2 * i + 0] = fmaf(f.x, w, acc[8 + 2 * i + 0]);
    acc[8 + 2 * i + 1] = fmaf(f.y, w, acc[8 + 2 * i + 1]);
  }
}

// Bilinear sample of one interleaved fp16 [H, W, C] layer into f32 acc[CH].
// Index/weight math in f32, identical to the reference formula.
__device__ __forceinline__ void sample_hwc16(const __half* __restrict__ t, int W,
                                             float gx, float gy, float acc[CH]) {
  const float W1 = (float)(W - 1);
  float ix = (gx + 1.0f) * 0.5f * W1;
  float iy = (gy + 1.0f) * 0.5f * W1;
  float ix0f = floorf(ix), iy0f = floorf(iy);
  float wx1 = ix - ix0f, wy1 = iy - iy0f;
  float wx0 = 1.0f - wx1, wy0 = 1.0f - wy1;
  float ix1f = ix0f + 1.0f, iy1f = iy0f + 1.0f;
  float vx0 = (ix0f >= 0.0f && ix0f <= W1) ? 1.0f : 0.0f;
  float vx1 = (ix1f >= 0.0f && ix1f <= W1) ? 1.0f : 0.0f;
  float vy0 = (iy0f >= 0.0f && iy0f <= W1) ? 1.0f : 0.0f;
  float vy1 = (iy1f >= 0.0f && iy1f <= W1) ? 1.0f : 0.0f;
  int x0 = min(max((int)ix0f, 0), W - 1);
  int x1 = min(max((int)ix1f, 0), W - 1);
  int y0 = min(max((int)iy0f, 0), W - 1);
  int y1 = min(max((int)iy1f, 0), W - 1);
  float w00 = wy0 * wx0 * vy0 * vx0;
  float w01 = wy0 * wx1 * vy0 * vx1;
  float w10 = wy1 * wx0 * vy1 * vx0;
  float w11 = wy1 * wx1 * vy1 * vx1;
  corner_fma(t, (size_t)y0 * W + x0, w00, acc);
  corner_fma(t, (size_t)y0 * W + x1, w01, acc);
  corner_fma(t, (size_t)y1 * W + x0, w10, acc);
  corner_fma(t, (size_t)y1 * W + x1, w11, acc);
}

__global__ __launch_bounds__(256) void gather_hwc16_kernel(
    const float* __restrict__ x, const float* __restrict__ msk,
    const __half* __restrict__ t1, const __half* __restrict__ t2,
    const __half* __restrict__ t3, const __half* __restrict__ t4,
    float* __restrict__ out) {
  int p = blockIdx.x * blockDim.x + threadIdx.x;
  int wo = p & 511, ho = (p >> 9) & 511, b = p >> 18;
  float2 g = ((const float2*)x)[p];
  float gx = g.x * 2.0f - 1.0f;
  float gy = g.y * 2.0f - 1.0f;
  float m = msk[p];
  float acc[CH];
#pragma unroll
  for (int c = 0; c < CH; ++c) acc[c] = 0.0f;
  sample_hwc16(t1, 1024, gx, gy, acc);
  sample_hwc16(t2, 512, gx, gy, acc);
  sample_hwc16(t3, 256, gx, gy, acc);
  sample_hwc16(t4, 128, gx, gy, acc);
  // out[b][c][ho][wo], c-stride = 512*512
  size_t obase = (size_t)b * (CH * 262144) + (size_t)ho * 512 + wo;
#pragma unroll
  for (int c = 0; c < CH; ++c) out[obase + (size_t)c * 262144] = acc[c] * m;
}

// ---------------------------------------------------------------------------
// Fallback: direct gather from native [C, H, W] f32 layout (if ws too small).
// ---------------------------------------------------------------------------
__device__ __forceinline__ void sample_chw(const float* __restrict__ t, int W,
                                           float gx, float gy, float acc[CH]) {
  const float W1 = (float)(W - 1);
  float ix = (gx + 1.0f) * 0.5f * W1;
  float iy = (gy + 1.0f) * 0.5f * W1;
  float ix0f = floorf(ix), iy0f = floorf(iy);
  float wx1 = ix - ix0f, wy1 = iy - iy0f;
  float wx0 = 1.0f - wx1, wy0 = 1.0f - wy1;
  float ix1f = ix0f + 1.0f, iy1f = iy0f + 1.0f;
  float vx0 = (ix0f >= 0.0f && ix0f <= W1) ? 1.0f : 0.0f;
  float vx1 = (ix1f >= 0.0f && ix1f <= W1) ? 1.0f : 0.0f;
  float vy0 = (iy0f >= 0.0f && iy0f <= W1) ? 1.0f : 0.0f;
  float vy1 = (iy1f >= 0.0f && iy1f <= W1) ? 1.0f : 0.0f;
  int x0 = min(max((int)ix0f, 0), W - 1);
  int x1 = min(max((int)ix1f, 0), W - 1);
  int y0 = min(max((int)iy0f, 0), W - 1);
  int y1 = min(max((int)iy1f, 0), W - 1);
  float w00 = wy0 * wx0 * vy0 * vx0;
  float w01 = wy0 * wx1 * vy0 * vx1;
  float w10 = wy1 * wx0 * vy1 * vx0;
  float w11 = wy1 * wx1 * vy1 * vx1;
  size_t HW = (size_t)W * W;
  const float* b00 = t + (size_t)y0 * W + x0;
  const float* b01 = t + (size_t)y0 * W + x1;
  const float* b10 = t + (size_t)y1 * W + x0;
  const float* b11 = t + (size_t)y1 * W + x1;
#pragma unroll
  for (int c = 0; c < CH; ++c) {
    float v00 = b00[c * HW], v01 = b01[c * HW], v10 = b10[c * HW], v11 = b11[c * HW];
    acc[c] = fmaf(v00, w00, fmaf(v01, w01, fmaf(v10, w10, fmaf(v11, w11, acc[c]))));
  }
}

__global__ __launch_bounds__(256) void gather_chw_kernel(
    const float* __restrict__ x, const float* __restrict__ msk,
    const float* __restrict__ l1, const float* __restrict__ l2,
    const float* __restrict__ l3, const float* __restrict__ l4,
    float* __restrict__ out) {
  int p = blockIdx.x * blockDim.x + threadIdx.x;
  int wo = p & 511, ho = (p >> 9) & 511, b = p >> 18;
  float2 g = ((const float2*)x)[p];
  float gx = g.x * 2.0f - 1.0f;
  float gy = g.y * 2.0f - 1.0f;
  float m = msk[p];
  float acc[CH];
#pragma unroll
  for (int c = 0; c < CH; ++c) acc[c] = 0.0f;
  sample_chw(l1, 1024, gx, gy, acc);
  sample_chw(l2, 512, gx, gy, acc);
  sample_chw(l3, 256, gx, gy, acc);
  sample_chw(l4, 128, gx, gy, acc);
  size_t obase = (size_t)b * (CH * 262144) + (size_t)ho * 512 + wo;
#pragma unroll
  for (int c = 0; c < CH; ++c) out[obase + (size_t)c * 262144] = acc[c] * m;
}

extern "C" void kernel_launch(void* const* d_in, const int* in_sizes, int n_in,
                              void* d_out, int out_size, void* d_ws, size_t ws_size,
                              hipStream_t stream) {
  const float* x   = (const float*)d_in[0];
  const float* msk = (const float*)d_in[1];
  const float* l1  = (const float*)d_in[2];
  const float* l2  = (const float*)d_in[3];
  const float* l3  = (const float*)d_in[4];
  const float* l4  = (const float*)d_in[5];
  float* out = (float*)d_out;

  const size_t need = (size_t)(1048576 + 262144 + 65536 + 16384) * CH * sizeof(__half);
  if (ws_size >= need) {
    __half* w1 = (__half*)d_ws;
    __half* w2 = w1 + (size_t)1048576 * CH;
    __half* w3 = w2 + (size_t)262144 * CH;
    __half* w4 = w3 + (size_t)65536 * CH;
    interleave_fp16_kernel<<<1048576 / 256, 256, 0, stream>>>(l1, w1, 1048576);
    interleave_fp16_kernel<<<262144 / 256, 256, 0, stream>>>(l2, w2, 262144);
    interleave_fp16_kernel<<<65536 / 256, 256, 0, stream>>>(l3, w3, 65536);
    interleave_fp16_kernel<<<16384 / 256, 256, 0, stream>>>(l4, w4, 16384);
    gather_hwc16_kernel<<<NPIX / 256, 256, 0, stream>>>(x, msk, w1, w2, w3, w4, out);
  } else {
    gather_chw_kernel<<<NPIX / 256, 256, 0, stream>>>(x, msk, l1, l2, l3, l4, out);
  }
}